// Round 12
// baseline (373.808 us; speedup 1.0000x reference)
//
#include <hip/hip_runtime.h>

// ---------------------------------------------------------------------------
// FlexibleGraphSAGE: 3-layer SAGEConv (mean aggregation).
//   per layer: out = mean_agg(h) @ Wl^T + bl + h @ Wr^T   (+ReLU on layers 0,1)
// R11 vs R10:
//   - layers 0/1: FUSED aggregate+GEMM. Block = 64 nodes; phase 1 gathers
//     mean-agg rows into padded LDS (64x136 halves, 272B stride: b128-aligned,
//     2-way bank alias only); phase 2 = R3 MFMA GEMM with A-frag from LDS.
//     Removes 2 dispatches + 25.6MB agg round-trip; block work = sum of 64
//     degrees (sigma ~3%) so imbalance is structural-zero; inter-block
//     gather/MFMA overlap.
//   - convert_all merged into hist dispatch (blockIdx split): 12 -> 9 launches.
//   R9/R10 evidence: gather is MSHR x latency bound (~3.4 TB/s random 256B);
//   occupancy/issue/imbalance tweaks all neutral -> attack structure instead.
// R9: layer-2 fp16 Rh + single out write. R8: layer-2 linearity reorder.
// R7: deterministic counting-sort CSR. R3: fp16 MFMA GEMM pipeline.
// ---------------------------------------------------------------------------

#define D_H 128
#define NBUCKET 196          // ceil(50000/256) node buckets of 256
#define EPB 8192             // edges per histogram/scatter block
#define NBLK 98              // ceil(800000/8192)

typedef _Float16 half8  __attribute__((ext_vector_type(8)));
typedef _Float16 half4v __attribute__((ext_vector_type(4)));
typedef float    floatx4 __attribute__((ext_vector_type(4)));

// ---------------- CSR step 1 + dtype conversion (merged dispatch) -----------
// blocks [0, NBLK): per-block histogram of dst buckets (LDS atomics only).
// blocks [NBLK, ...): fp32->fp16 conversion of x and the 6 weight matrices.
__global__ __launch_bounds__(256) void hist_convert_kernel(
        const int* __restrict__ dst, int* __restrict__ histo, int E,
        const float* __restrict__ x, _Float16* __restrict__ xh, int n4,
        const float* __restrict__ w0, const float* __restrict__ w1,
        const float* __restrict__ w2, const float* __restrict__ w3,
        const float* __restrict__ w4, const float* __restrict__ w5,
        _Float16* __restrict__ o0, _Float16* __restrict__ o1,
        _Float16* __restrict__ o2, _Float16* __restrict__ o3,
        _Float16* __restrict__ o4, _Float16* __restrict__ o5) {
    if (blockIdx.x < NBLK) {
        __shared__ int h[NBUCKET];
        for (int i = threadIdx.x; i < NBUCKET; i += 256) h[i] = 0;
        __syncthreads();
        int base = blockIdx.x * EPB;
        int end = min(base + EPB, E);
        for (int i = base + threadIdx.x; i < end; i += 256)
            atomicAdd(&h[dst[i] >> 8], 1);
        __syncthreads();
        for (int i = threadIdx.x; i < NBUCKET; i += 256)
            histo[blockIdx.x * NBUCKET + i] = h[i];
        return;
    }
    int i = (blockIdx.x - NBLK) * 256 + threadIdx.x;
    const float* in; _Float16* out; int j;
    if (i < n4) { in = x; out = xh; j = i; }
    else {
        int k = i - n4;
        if      (k <  4096) { in = w0; out = o0; j = k; }
        else if (k <  8192) { in = w1; out = o1; j = k - 4096; }
        else if (k < 12288) { in = w2; out = o2; j = k - 8192; }
        else if (k < 16384) { in = w3; out = o3; j = k - 12288; }
        else if (k < 18432) { in = w4; out = o4; j = k - 16384; }
        else if (k < 20480) { in = w5; out = o5; j = k - 18432; }
        else return;
    }
    float4 v = ((const float4*)in)[j];
    half4v o = { (_Float16)v.x, (_Float16)v.y, (_Float16)v.z, (_Float16)v.w };
    ((half4v*)out)[j] = o;
}

__global__ __launch_bounds__(256) void scan_hist_kernel(const int* __restrict__ histo,
                                                        int* __restrict__ offs,
                                                        int* __restrict__ boff,
                                                        int* __restrict__ row_ptr, int n) {
    __shared__ int s[256];
    int t = threadIdx.x;
    int sum = 0;
    if (t < NBUCKET) {
        for (int b = 0; b < NBLK; ++b) {
            offs[b * NBUCKET + t] = sum;
            sum += histo[b * NBUCKET + t];
        }
    }
    s[t] = (t < NBUCKET) ? sum : 0;
    int tot = s[t];
    __syncthreads();
    for (int off = 1; off < 256; off <<= 1) {
        int tmp = (t >= off) ? s[t - off] : 0;
        __syncthreads();
        s[t] += tmp;
        __syncthreads();
    }
    int base = s[t] - tot;
    if (t < NBUCKET) boff[t] = base;
    if (t == 255) { boff[NBUCKET] = s[255]; row_ptr[n] = s[255]; }
    __syncthreads();
    if (t < NBUCKET)
        for (int b = 0; b < NBLK; ++b)
            offs[b * NBUCKET + t] += base;
}

__global__ __launch_bounds__(256) void scatter_kernel(const int* __restrict__ src,
                                                      const int* __restrict__ dst,
                                                      const int* __restrict__ offs,
                                                      unsigned int* __restrict__ bedge, int E) {
    __shared__ int lcur[NBUCKET];
    for (int i = threadIdx.x; i < NBUCKET; i += 256)
        lcur[i] = offs[blockIdx.x * NBUCKET + i];
    __syncthreads();
    int base = blockIdx.x * EPB;
    int end = min(base + EPB, E);
    for (int i = base + threadIdx.x; i < end; i += 256) {
        int d = dst[i];
        int pos = atomicAdd(&lcur[d >> 8], 1);
        bedge[pos] = ((unsigned int)(d & 255) << 16) | (unsigned int)src[i];
    }
}

__global__ __launch_bounds__(256) void bucket_build_kernel(const unsigned int* __restrict__ bedge,
                                                           const int* __restrict__ boff,
                                                           int* __restrict__ row_ptr,
                                                           float* __restrict__ inv_deg,
                                                           int* __restrict__ col, int n) {
    __shared__ int sdeg[256];
    __shared__ int sscan[256];
    __shared__ int lcur[256];
    const int b = blockIdx.x;
    const int t = threadIdx.x;
    const int base = boff[b];
    const int bend = boff[b + 1];
    sdeg[t] = 0;
    __syncthreads();
    for (int i = base + t; i < bend; i += 256)
        atomicAdd(&sdeg[bedge[i] >> 16], 1);
    __syncthreads();
    int d = sdeg[t];
    sscan[t] = d;
    __syncthreads();
    for (int off = 1; off < 256; off <<= 1) {
        int tmp = (t >= off) ? sscan[t - off] : 0;
        __syncthreads();
        sscan[t] += tmp;
        __syncthreads();
    }
    int excl = sscan[t] - d;
    int node = b * 256 + t;
    if (node < n) {
        row_ptr[node] = base + excl;
        inv_deg[node] = 1.0f / (float)max(d, 1);
    }
    lcur[t] = excl;
    __syncthreads();
    for (int i = base + t; i < bend; i += 256) {
        unsigned int v = bedge[i];
        int pos = atomicAdd(&lcur[v >> 16], 1);
        col[base + pos] = (int)(v & 0xffffu);
    }
}

// ---------------- FUSED aggregate + GEMM (layers 0/1) ----------------
// Block = 64 nodes, 128 threads (2 waves).
// Phase 1: wave w aggregates nodes [block0+32w, block0+32w+32) with the R10
//   quarter-wave gather (16 lanes x half8; 4 rows in flight); node loop is
//   wave-uniform so every __shfl runs with the full wave active (R6 rule).
//   Mean row written to LDS aggs[r][.] (stride 136 halves = 272B: 16B-aligned
//   b128 rows, 2-way bank alias only).
// Phase 2: R3-proven MFMA GEMM; A-frag half 'a' (agg) from LDS, half 'h' and
//   B-frags from global. out = relu(agg@Wa^T + h@Wh^T + bias) in fp16.
__global__ __launch_bounds__(128) void fused_agg_gemm_kernel(
        const _Float16* __restrict__ h,
        const int* __restrict__ row_ptr, const int* __restrict__ col,
        const float* __restrict__ inv_deg,
        const _Float16* __restrict__ Wa, const _Float16* __restrict__ Wh,
        const float* __restrict__ bias,
        _Float16* __restrict__ out_h, int N) {
    __shared__ _Float16 aggs[64][136];   // 17.4 KB
    const int wave = threadIdx.x >> 6;
    const int lane = threadIdx.x & 63;
    const int quarter = lane >> 4;
    const int r16 = lane & 15;
    const int block0 = blockIdx.x * 64;

    // ---- phase 1: aggregate 32 nodes per wave ----
    const int goff = r16 << 3;           // half8 slice within 128-dim row
    for (int idx = 0; idx < 32; ++idx) {
        int lrow = wave * 32 + idx;
        int node = block0 + lrow;
        if (node >= N) {                 // wave-uniform branch
            if (quarter == 0)
                *(half8*)&aggs[lrow][goff] = (half8){0,0,0,0,0,0,0,0};
            continue;
        }
        int beg = row_ptr[node];
        int end = row_ptr[node + 1];
        float a0f = 0.f, a1f = 0.f, a2f = 0.f, a3f = 0.f;
        float a4f = 0.f, a5f = 0.f, a6f = 0.f, a7f = 0.f;
        for (int base = beg; base < end; base += 64) {
            int m = end - base;
            if (m > 64) m = 64;
            int myc = (lane < m) ? col[base + lane] : 0;
            int t = 0;
            for (; t + 4 <= (m >> 2); t += 4) {     // uniform bound, no guards
                int u0 = __shfl(myc, ((t + 0) << 2) + quarter);
                int u1 = __shfl(myc, ((t + 1) << 2) + quarter);
                int u2 = __shfl(myc, ((t + 2) << 2) + quarter);
                int u3 = __shfl(myc, ((t + 3) << 2) + quarter);
                half8 v0 = *(const half8*)&h[(size_t)u0 * D_H + goff];
                half8 v1 = *(const half8*)&h[(size_t)u1 * D_H + goff];
                half8 v2 = *(const half8*)&h[(size_t)u2 * D_H + goff];
                half8 v3 = *(const half8*)&h[(size_t)u3 * D_H + goff];
                a0f += (float)v0[0] + (float)v1[0] + (float)v2[0] + (float)v3[0];
                a1f += (float)v0[1] + (float)v1[1] + (float)v2[1] + (float)v3[1];
                a2f += (float)v0[2] + (float)v1[2] + (float)v2[2] + (float)v3[2];
                a3f += (float)v0[3] + (float)v1[3] + (float)v2[3] + (float)v3[3];
                a4f += (float)v0[4] + (float)v1[4] + (float)v2[4] + (float)v3[4];
                a5f += (float)v0[5] + (float)v1[5] + (float)v2[5] + (float)v3[5];
                a6f += (float)v0[6] + (float)v1[6] + (float)v2[6] + (float)v3[6];
                a7f += (float)v0[7] + (float)v1[7] + (float)v2[7] + (float)v3[7];
            }
            int smax = (m + 3) >> 2;                // uniform tail
            for (; t < smax; ++t) {
                int j = (t << 2) + quarter;
                int u = __shfl(myc, j);             // full wave active
                if (j < m) {
                    half8 v = *(const half8*)&h[(size_t)u * D_H + goff];
                    a0f += (float)v[0]; a1f += (float)v[1];
                    a2f += (float)v[2]; a3f += (float)v[3];
                    a4f += (float)v[4]; a5f += (float)v[5];
                    a6f += (float)v[6]; a7f += (float)v[7];
                }
            }
        }
        // butterfly: lanes i, i+16, i+32, i+48 hold the same slice
        a0f += __shfl(a0f, lane + 16); a1f += __shfl(a1f, lane + 16);
        a2f += __shfl(a2f, lane + 16); a3f += __shfl(a3f, lane + 16);
        a4f += __shfl(a4f, lane + 16); a5f += __shfl(a5f, lane + 16);
        a6f += __shfl(a6f, lane + 16); a7f += __shfl(a7f, lane + 16);
        a0f += __shfl(a0f, lane + 32); a1f += __shfl(a1f, lane + 32);
        a2f += __shfl(a2f, lane + 32); a3f += __shfl(a3f, lane + 32);
        a4f += __shfl(a4f, lane + 32); a5f += __shfl(a5f, lane + 32);
        a6f += __shfl(a6f, lane + 32); a7f += __shfl(a7f, lane + 32);
        if (quarter == 0) {
            float s = inv_deg[node];
            half8 o = { (_Float16)(a0f * s), (_Float16)(a1f * s),
                        (_Float16)(a2f * s), (_Float16)(a3f * s),
                        (_Float16)(a4f * s), (_Float16)(a5f * s),
                        (_Float16)(a6f * s), (_Float16)(a7f * s) };
            *(half8*)&aggs[lrow][goff] = o;
        }
    }
    __syncthreads();

    // ---- phase 2: GEMM (NT=8, relu, fp16 out) ----
    const int quad = lane >> 4;
    const int base = block0 + wave * 32;
    const int koff = quad * 8;

    floatx4 acc[2][8];
    #pragma unroll
    for (int s = 0; s < 2; ++s)
        #pragma unroll
        for (int j = 0; j < 8; ++j)
            acc[s][j] = (floatx4){0.f, 0.f, 0.f, 0.f};

    #pragma unroll
    for (int k0 = 0; k0 < 128; k0 += 32) {
        // agg half from LDS
        half8 a0 = *(const half8*)&aggs[wave * 32 + r16][k0 + koff];
        half8 a1 = *(const half8*)&aggs[wave * 32 + 16 + r16][k0 + koff];
        // h half from global
        half8 c0 = *(const half8*)&h[(size_t)(base + r16) * 128 + k0 + koff];
        half8 c1 = *(const half8*)&h[(size_t)(base + 16 + r16) * 128 + k0 + koff];
        #pragma unroll
        for (int j = 0; j < 8; ++j) {
            half8 ba = *(const half8*)&Wa[(size_t)(j * 16 + r16) * 128 + k0 + koff];
            half8 bh = *(const half8*)&Wh[(size_t)(j * 16 + r16) * 128 + k0 + koff];
            acc[0][j] = __builtin_amdgcn_mfma_f32_16x16x32_f16(a0, ba, acc[0][j], 0, 0, 0);
            acc[1][j] = __builtin_amdgcn_mfma_f32_16x16x32_f16(a1, ba, acc[1][j], 0, 0, 0);
            acc[0][j] = __builtin_amdgcn_mfma_f32_16x16x32_f16(c0, bh, acc[0][j], 0, 0, 0);
            acc[1][j] = __builtin_amdgcn_mfma_f32_16x16x32_f16(c1, bh, acc[1][j], 0, 0, 0);
        }
    }

    #pragma unroll
    for (int s = 0; s < 2; ++s) {
        #pragma unroll
        for (int i = 0; i < 4; ++i) {
            int r = base + s * 16 + quad * 4 + i;
            if (r >= N) continue;
            #pragma unroll
            for (int j = 0; j < 8; ++j) {
                int c = j * 16 + r16;
                float v = fmaxf(acc[s][j][i] + bias[c], 0.f);
                out_h[(size_t)r * 128 + c] = (_Float16)v;
            }
        }
    }
}

// ---------------- layer-2 finish: out = Rh + inv_deg * sum T[neighbors] -----
// 64-dim rows (128B): 16 lanes x half4 (8B), quarter-wave, 2 nodes/block.
__global__ __launch_bounds__(128, 8) void aggregate_add64_kernel(
        const _Float16* __restrict__ T,
        const _Float16* __restrict__ Rh,
        const int* __restrict__ row_ptr,
        const int* __restrict__ col,
        const float* __restrict__ inv_deg,
        float* __restrict__ out, int n) {
    int wave = threadIdx.x >> 6;
    int lane = threadIdx.x & 63;
    int node = blockIdx.x * 2 + wave;
    if (node >= n) return;
    int beg = row_ptr[node];
    int end = row_ptr[node + 1];
    const int quarter = lane >> 4;
    const int off = (lane & 15) << 2;
    float a0f = 0.f, a1f = 0.f, a2f = 0.f, a3f = 0.f;
    for (int base = beg; base < end; base += 64) {
        int m = end - base;
        if (m > 64) m = 64;
        int myc = (lane < m) ? col[base + lane] : 0;
        int t = 0;
        for (; t + 4 <= (m >> 2); t += 4) {
            int u0 = __shfl(myc, ((t + 0) << 2) + quarter);
            int u1 = __shfl(myc, ((t + 1) << 2) + quarter);
            int u2 = __shfl(myc, ((t + 2) << 2) + quarter);
            int u3 = __shfl(myc, ((t + 3) << 2) + quarter);
            half4v v0 = *(const half4v*)&T[(size_t)u0 * 64 + off];
            half4v v1 = *(const half4v*)&T[(size_t)u1 * 64 + off];
            half4v v2 = *(const half4v*)&T[(size_t)u2 * 64 + off];
            half4v v3 = *(const half4v*)&T[(size_t)u3 * 64 + off];
            a0f += (float)v0[0] + (float)v1[0] + (float)v2[0] + (float)v3[0];
            a1f += (float)v0[1] + (float)v1[1] + (float)v2[1] + (float)v3[1];
            a2f += (float)v0[2] + (float)v1[2] + (float)v2[2] + (float)v3[2];
            a3f += (float)v0[3] + (float)v1[3] + (float)v2[3] + (float)v3[3];
        }
        int smax = (m + 3) >> 2;
        for (; t < smax; ++t) {
            int j = (t << 2) + quarter;
            int u = __shfl(myc, j);
            if (j < m) {
                half4v v = *(const half4v*)&T[(size_t)u * 64 + off];
                a0f += (float)v[0]; a1f += (float)v[1];
                a2f += (float)v[2]; a3f += (float)v[3];
            }
        }
    }
    a0f += __shfl(a0f, lane + 16); a1f += __shfl(a1f, lane + 16);
    a2f += __shfl(a2f, lane + 16); a3f += __shfl(a3f, lane + 16);
    a0f += __shfl(a0f, lane + 32); a1f += __shfl(a1f, lane + 32);
    a2f += __shfl(a2f, lane + 32); a3f += __shfl(a3f, lane + 32);
    if (quarter == 0) {
        float s = inv_deg[node];
        half4v r = *(const half4v*)&Rh[(size_t)node * 64 + off];
        float4 o;
        o.x = (float)r[0] + a0f * s;
        o.y = (float)r[1] + a1f * s;
        o.z = (float)r[2] + a2f * s;
        o.w = (float)r[3] + a3f * s;
        *(float4*)&out[(size_t)node * 64 + off] = o;
    }
}

// ---- dual GEMM, layer 2: T = B@Wl^T (fp16), Rh = B@Wr^T + bias (fp16) ----
__global__ __launch_bounds__(128) void gemm_dual_kernel(
        const _Float16* __restrict__ B, const _Float16* __restrict__ Wl,
        const _Float16* __restrict__ Wr, const float* __restrict__ bias,
        _Float16* __restrict__ T, _Float16* __restrict__ Rh, int N) {
    const int wave = threadIdx.x >> 6;
    const int lane = threadIdx.x & 63;
    const int r16 = lane & 15;
    const int quad = lane >> 4;
    const int base = blockIdx.x * 64 + wave * 32;
    const int koff = quad * 8;

    floatx4 accT[2][4], accR[2][4];
    #pragma unroll
    for (int s = 0; s < 2; ++s)
        #pragma unroll
        for (int j = 0; j < 4; ++j) {
            accT[s][j] = (floatx4){0.f, 0.f, 0.f, 0.f};
            accR[s][j] = (floatx4){0.f, 0.f, 0.f, 0.f};
        }

    #pragma unroll
    for (int k0 = 0; k0 < 128; k0 += 32) {
        half8 a0 = *(const half8*)&B[(size_t)(base + r16) * 128 + k0 + koff];
        half8 a1 = *(const half8*)&B[(size_t)(base + 16 + r16) * 128 + k0 + koff];
        #pragma unroll
        for (int j = 0; j < 4; ++j) {
            half8 bl = *(const half8*)&Wl[(size_t)(j * 16 + r16) * 128 + k0 + koff];
            half8 br = *(const half8*)&Wr[(size_t)(j * 16 + r16) * 128 + k0 + koff];
            accT[0][j] = __builtin_amdgcn_mfma_f32_16x16x32_f16(a0, bl, accT[0][j], 0, 0, 0);
            accT[1][j] = __builtin_amdgcn_mfma_f32_16x16x32_f16(a1, bl, accT[1][j], 0, 0, 0);
            accR[0][j] = __builtin_amdgcn_mfma_f32_16x16x32_f16(a0, br, accR[0][j], 0, 0, 0);
            accR[1][j] = __builtin_amdgcn_mfma_f32_16x16x32_f16(a1, br, accR[1][j], 0, 0, 0);
        }
    }

    #pragma unroll
    for (int s = 0; s < 2; ++s) {
        #pragma unroll
        for (int i = 0; i < 4; ++i) {
            int r = base + s * 16 + quad * 4 + i;
            if (r >= N) continue;
            #pragma unroll
            for (int j = 0; j < 4; ++j) {
                int c = j * 16 + r16;
                T[(size_t)r * 64 + c]  = (_Float16)accT[s][j][i];
                Rh[(size_t)r * 64 + c] = (_Float16)(accR[s][j][i] + bias[c]);
            }
        }
    }
}

extern "C" void kernel_launch(void* const* d_in, const int* in_sizes, int n_in,
                              void* d_out, int out_size, void* d_ws, size_t ws_size,
                              hipStream_t stream) {
    const float* x   = (const float*)d_in[0];
    const int*   edge = (const int*)d_in[1];   // int32: [2, E]
    const float* Wl0 = (const float*)d_in[2];
    const float* bl0 = (const float*)d_in[3];
    const float* Wr0 = (const float*)d_in[4];
    const float* Wl1 = (const float*)d_in[5];
    const float* bl1 = (const float*)d_in[6];
    const float* Wr1 = (const float*)d_in[7];
    const float* Wl2 = (const float*)d_in[8];
    const float* bl2 = (const float*)d_in[9];
    const float* Wr2 = (const float*)d_in[10];
    float* out = (float*)d_out;

    const int N = in_sizes[0] / D_H;   // 50000
    const int E = in_sizes[1] / 2;     // 800000
    const int* src = edge;
    const int* dst = edge + E;

    const int gx = (N + 63) / 64;
    const int Np = gx * 64;
    const size_t HBYTES = (size_t)Np * D_H * 2;   // 12.8MB per fp16 node matrix

    // ---- time-multiplexed workspace (~42MB) ----
    char* w = (char*)d_ws;
    char* P0 = w;  w += HBYTES;
    char* P1 = w;  w += HBYTES;
    char* P2 = w;  w += HBYTES;
    _Float16* Wl0h = (_Float16*)w;  w += (size_t)128 * 128 * 2;
    _Float16* Wr0h = (_Float16*)w;  w += (size_t)128 * 128 * 2;
    _Float16* Wl1h = (_Float16*)w;  w += (size_t)128 * 128 * 2;
    _Float16* Wr1h = (_Float16*)w;  w += (size_t)128 * 128 * 2;
    _Float16* Wl2h = (_Float16*)w;  w += (size_t)64 * 128 * 2;
    _Float16* Wr2h = (_Float16*)w;  w += (size_t)64 * 128 * 2;
    int* row_ptr = (int*)w;      w += (size_t)(N + 16) * 4;
    float* inv_deg = (float*)w;  w += (size_t)N * 4;
    int* col     = (int*)w;      w += (size_t)E * 4;
    int* histo   = (int*)w;      w += (size_t)NBLK * NBUCKET * 4;
    int* offs    = (int*)w;      w += (size_t)NBLK * NBUCKET * 4;
    int* boff    = (int*)w;      w += (size_t)(NBUCKET + 1) * 4;

    _Float16* xh   = (_Float16*)P0;
    _Float16* Bh   = (_Float16*)P0;          // xh dead after fused layer-0
    unsigned int* bedge = (unsigned int*)P1; // 3.2MB, dead after bucket_build
    _Float16* Ah   = (_Float16*)P1;
    _Float16* T    = (_Float16*)P2;                       // layer-2 T (6.4MB)
    _Float16* Rh   = (_Float16*)(P2 + HBYTES / 2);        // layer-2 Rh (6.4MB)

    // ---- CSR step 1 + conversions (one dispatch) ----
    const int n4 = N * D_H / 4;
    const int conv_blocks = (n4 + 20480 + 255) / 256;
    hist_convert_kernel<<<NBLK + conv_blocks, 256, 0, stream>>>(
        dst, histo, E, x, xh, n4,
        Wl0, Wr0, Wl1, Wr1, Wl2, Wr2,
        Wl0h, Wr0h, Wl1h, Wr1h, Wl2h, Wr2h);

    // ---- CSR steps 2-4 ----
    scan_hist_kernel<<<1, 256, 0, stream>>>(histo, offs, boff, row_ptr, N);
    scatter_kernel<<<NBLK, 256, 0, stream>>>(src, dst, offs, bedge, E);
    bucket_build_kernel<<<NBUCKET, 256, 0, stream>>>(bedge, boff, row_ptr, inv_deg, col, N);

    // ---- layer 0 (fused): Ah = relu(mean_agg(xh)@Wl0^T + bl0 + xh@Wr0^T) ----
    fused_agg_gemm_kernel<<<gx, 128, 0, stream>>>(xh, row_ptr, col, inv_deg,
                                                  Wl0h, Wr0h, bl0, Ah, N);

    // ---- layer 1 (fused): Bh = relu(mean_agg(Ah)@Wl1^T + bl1 + Ah@Wr1^T) ----
    fused_agg_gemm_kernel<<<gx, 128, 0, stream>>>(Ah, row_ptr, col, inv_deg,
                                                  Wl1h, Wr1h, bl1, Bh, N);

    // ---- layer 2 (reordered): T = Bh@Wl2^T, Rh = Bh@Wr2^T + bias (fp16),
    //      then out = Rh + inv_deg * (A @ T) with 64-dim (128B) gathers ----
    gemm_dual_kernel<<<gx, 128, 0, stream>>>(Bh, Wl2h, Wr2h, bl2, T, Rh, N);
    aggregate_add64_kernel<<<(N + 1) / 2, 128, 0, stream>>>(T, Rh, row_ptr, col,
                                                            inv_deg, out, N);
}

// Round 13
// 293.035 us; speedup vs baseline: 1.2756x; 1.2756x over previous
//
#include <hip/hip_runtime.h>

// ---------------------------------------------------------------------------
// FlexibleGraphSAGE: 3-layer SAGEConv (mean aggregation).
//   per layer: out = mean_agg(h) @ Wl^T + bl + h @ Wr^T   (+ReLU on layers 0,1)
// R12: REVERT to R10 best-known (295.6us). R11's agg+GEMM fusion regressed
//   (96us/layer): it cut gather concurrency 25000 waves -> 1564 waves; the
//   gather is latency x outstanding-miss bound, so concurrency is everything.
//   Kept from R11 only the hist+convert launch merge (harmless, -1 dispatch).
// Floor evidence: R9 (occupancy) / R10 (issue-rate, imbalance) / R11 (fusion)
//   all neutral-or-worse -> aggregate pinned at ~3 TB/s random-256B fabric
//   ceiling; bytes already minimal in fp16 (fp8 breaches error budget).
// R10: quarter-wave gather (16 lanes x half8, 4 rows in flight), 2 nodes/blk.
// R9: layer-2 fp16 Rh + single out write. R8: layer-2 linearity reorder.
// R7: deterministic counting-sort CSR. R3: fp16 MFMA GEMM pipeline.
// ---------------------------------------------------------------------------

#define D_H 128
#define NBUCKET 196          // ceil(50000/256) node buckets of 256
#define EPB 8192             // edges per histogram/scatter block
#define NBLK 98              // ceil(800000/8192)

typedef _Float16 half8  __attribute__((ext_vector_type(8)));
typedef _Float16 half4v __attribute__((ext_vector_type(4)));
typedef float    floatx4 __attribute__((ext_vector_type(4)));

// ---------------- CSR step 1 + dtype conversion (merged dispatch) -----------
__global__ __launch_bounds__(256) void hist_convert_kernel(
        const int* __restrict__ dst, int* __restrict__ histo, int E,
        const float* __restrict__ x, _Float16* __restrict__ xh, int n4,
        const float* __restrict__ w0, const float* __restrict__ w1,
        const float* __restrict__ w2, const float* __restrict__ w3,
        const float* __restrict__ w4, const float* __restrict__ w5,
        _Float16* __restrict__ o0, _Float16* __restrict__ o1,
        _Float16* __restrict__ o2, _Float16* __restrict__ o3,
        _Float16* __restrict__ o4, _Float16* __restrict__ o5) {
    if (blockIdx.x < NBLK) {
        __shared__ int h[NBUCKET];
        for (int i = threadIdx.x; i < NBUCKET; i += 256) h[i] = 0;
        __syncthreads();
        int base = blockIdx.x * EPB;
        int end = min(base + EPB, E);
        for (int i = base + threadIdx.x; i < end; i += 256)
            atomicAdd(&h[dst[i] >> 8], 1);
        __syncthreads();
        for (int i = threadIdx.x; i < NBUCKET; i += 256)
            histo[blockIdx.x * NBUCKET + i] = h[i];
        return;
    }
    int i = (blockIdx.x - NBLK) * 256 + threadIdx.x;
    const float* in; _Float16* out; int j;
    if (i < n4) { in = x; out = xh; j = i; }
    else {
        int k = i - n4;
        if      (k <  4096) { in = w0; out = o0; j = k; }
        else if (k <  8192) { in = w1; out = o1; j = k - 4096; }
        else if (k < 12288) { in = w2; out = o2; j = k - 8192; }
        else if (k < 16384) { in = w3; out = o3; j = k - 12288; }
        else if (k < 18432) { in = w4; out = o4; j = k - 16384; }
        else if (k < 20480) { in = w5; out = o5; j = k - 18432; }
        else return;
    }
    float4 v = ((const float4*)in)[j];
    half4v o = { (_Float16)v.x, (_Float16)v.y, (_Float16)v.z, (_Float16)v.w };
    ((half4v*)out)[j] = o;
}

__global__ __launch_bounds__(256) void scan_hist_kernel(const int* __restrict__ histo,
                                                        int* __restrict__ offs,
                                                        int* __restrict__ boff,
                                                        int* __restrict__ row_ptr, int n) {
    __shared__ int s[256];
    int t = threadIdx.x;
    int sum = 0;
    if (t < NBUCKET) {
        for (int b = 0; b < NBLK; ++b) {
            offs[b * NBUCKET + t] = sum;
            sum += histo[b * NBUCKET + t];
        }
    }
    s[t] = (t < NBUCKET) ? sum : 0;
    int tot = s[t];
    __syncthreads();
    for (int off = 1; off < 256; off <<= 1) {
        int tmp = (t >= off) ? s[t - off] : 0;
        __syncthreads();
        s[t] += tmp;
        __syncthreads();
    }
    int base = s[t] - tot;
    if (t < NBUCKET) boff[t] = base;
    if (t == 255) { boff[NBUCKET] = s[255]; row_ptr[n] = s[255]; }
    __syncthreads();
    if (t < NBUCKET)
        for (int b = 0; b < NBLK; ++b)
            offs[b * NBUCKET + t] += base;
}

__global__ __launch_bounds__(256) void scatter_kernel(const int* __restrict__ src,
                                                      const int* __restrict__ dst,
                                                      const int* __restrict__ offs,
                                                      unsigned int* __restrict__ bedge, int E) {
    __shared__ int lcur[NBUCKET];
    for (int i = threadIdx.x; i < NBUCKET; i += 256)
        lcur[i] = offs[blockIdx.x * NBUCKET + i];
    __syncthreads();
    int base = blockIdx.x * EPB;
    int end = min(base + EPB, E);
    for (int i = base + threadIdx.x; i < end; i += 256) {
        int d = dst[i];
        int pos = atomicAdd(&lcur[d >> 8], 1);
        bedge[pos] = ((unsigned int)(d & 255) << 16) | (unsigned int)src[i];
    }
}

__global__ __launch_bounds__(256) void bucket_build_kernel(const unsigned int* __restrict__ bedge,
                                                           const int* __restrict__ boff,
                                                           int* __restrict__ row_ptr,
                                                           float* __restrict__ inv_deg,
                                                           int* __restrict__ col, int n) {
    __shared__ int sdeg[256];
    __shared__ int sscan[256];
    __shared__ int lcur[256];
    const int b = blockIdx.x;
    const int t = threadIdx.x;
    const int base = boff[b];
    const int bend = boff[b + 1];
    sdeg[t] = 0;
    __syncthreads();
    for (int i = base + t; i < bend; i += 256)
        atomicAdd(&sdeg[bedge[i] >> 16], 1);
    __syncthreads();
    int d = sdeg[t];
    sscan[t] = d;
    __syncthreads();
    for (int off = 1; off < 256; off <<= 1) {
        int tmp = (t >= off) ? sscan[t - off] : 0;
        __syncthreads();
        sscan[t] += tmp;
        __syncthreads();
    }
    int excl = sscan[t] - d;
    int node = b * 256 + t;
    if (node < n) {
        row_ptr[node] = base + excl;
        inv_deg[node] = 1.0f / (float)max(d, 1);
    }
    lcur[t] = excl;
    __syncthreads();
    for (int i = base + t; i < bend; i += 256) {
        unsigned int v = bedge[i];
        int pos = atomicAdd(&lcur[v >> 16], 1);
        col[base + pos] = (int)(v & 0xffffu);
    }
}

// ---------------- aggregate: mean of neighbor rows (128-dim) ----------------
// 2 nodes per 128-thread block (1 wave each; independent retire).
// Quarter-wave: 16 lanes x half8 (16B) per 256B row; 4 rows in flight per
// load-issue. Uniform loop bounds; shfl always full-wave (R6 rule).
__global__ __launch_bounds__(128, 8) void aggregate_kernel(const _Float16* __restrict__ h,
                                                           const int* __restrict__ row_ptr,
                                                           const int* __restrict__ col,
                                                           const float* __restrict__ inv_deg,
                                                           _Float16* __restrict__ agg, int n) {
    int wave = threadIdx.x >> 6;
    int lane = threadIdx.x & 63;
    int node = blockIdx.x * 2 + wave;
    if (node >= n) return;
    int beg = row_ptr[node];
    int end = row_ptr[node + 1];
    const int quarter = lane >> 4;
    const int off = (lane & 15) << 3;     // half8 slice: 16 lanes x 8 halves = 128
    float a0f = 0.f, a1f = 0.f, a2f = 0.f, a3f = 0.f;
    float a4f = 0.f, a5f = 0.f, a6f = 0.f, a7f = 0.f;
    for (int base = beg; base < end; base += 64) {
        int m = end - base;
        if (m > 64) m = 64;
        int myc = (lane < m) ? col[base + lane] : 0;
        int t = 0;
        // x4 main: uniform bound; j = 4(t+i)+quarter <= m-1, no guards.
        for (; t + 4 <= (m >> 2); t += 4) {
            int u0 = __shfl(myc, ((t + 0) << 2) + quarter);
            int u1 = __shfl(myc, ((t + 1) << 2) + quarter);
            int u2 = __shfl(myc, ((t + 2) << 2) + quarter);
            int u3 = __shfl(myc, ((t + 3) << 2) + quarter);
            half8 v0 = *(const half8*)&h[(size_t)u0 * D_H + off];
            half8 v1 = *(const half8*)&h[(size_t)u1 * D_H + off];
            half8 v2 = *(const half8*)&h[(size_t)u2 * D_H + off];
            half8 v3 = *(const half8*)&h[(size_t)u3 * D_H + off];
            a0f += (float)v0[0] + (float)v1[0] + (float)v2[0] + (float)v3[0];
            a1f += (float)v0[1] + (float)v1[1] + (float)v2[1] + (float)v3[1];
            a2f += (float)v0[2] + (float)v1[2] + (float)v2[2] + (float)v3[2];
            a3f += (float)v0[3] + (float)v1[3] + (float)v2[3] + (float)v3[3];
            a4f += (float)v0[4] + (float)v1[4] + (float)v2[4] + (float)v3[4];
            a5f += (float)v0[5] + (float)v1[5] + (float)v2[5] + (float)v3[5];
            a6f += (float)v0[6] + (float)v1[6] + (float)v2[6] + (float)v3[6];
            a7f += (float)v0[7] + (float)v1[7] + (float)v2[7] + (float)v3[7];
        }
        // uniform tail; shfl full-wave, load+add guarded (j < m)
        int smax = (m + 3) >> 2;
        for (; t < smax; ++t) {
            int j = (t << 2) + quarter;
            int u = __shfl(myc, j);
            if (j < m) {
                half8 v = *(const half8*)&h[(size_t)u * D_H + off];
                a0f += (float)v[0]; a1f += (float)v[1];
                a2f += (float)v[2]; a3f += (float)v[3];
                a4f += (float)v[4]; a5f += (float)v[5];
                a6f += (float)v[6]; a7f += (float)v[7];
            }
        }
    }
    // two-stage butterfly: lanes i, i+16, i+32, i+48 hold the same slice
    a0f += __shfl(a0f, lane + 16); a1f += __shfl(a1f, lane + 16);
    a2f += __shfl(a2f, lane + 16); a3f += __shfl(a3f, lane + 16);
    a4f += __shfl(a4f, lane + 16); a5f += __shfl(a5f, lane + 16);
    a6f += __shfl(a6f, lane + 16); a7f += __shfl(a7f, lane + 16);
    a0f += __shfl(a0f, lane + 32); a1f += __shfl(a1f, lane + 32);
    a2f += __shfl(a2f, lane + 32); a3f += __shfl(a3f, lane + 32);
    a4f += __shfl(a4f, lane + 32); a5f += __shfl(a5f, lane + 32);
    a6f += __shfl(a6f, lane + 32); a7f += __shfl(a7f, lane + 32);
    if (quarter == 0) {
        float s = inv_deg[node];
        half8 o = { (_Float16)(a0f * s), (_Float16)(a1f * s),
                    (_Float16)(a2f * s), (_Float16)(a3f * s),
                    (_Float16)(a4f * s), (_Float16)(a5f * s),
                    (_Float16)(a6f * s), (_Float16)(a7f * s) };
        *(half8*)&agg[(size_t)node * D_H + off] = o;
    }
}

// ---------------- layer-2 finish: out = Rh + inv_deg * sum T[neighbors] -----
__global__ __launch_bounds__(128, 8) void aggregate_add64_kernel(
        const _Float16* __restrict__ T,
        const _Float16* __restrict__ Rh,
        const int* __restrict__ row_ptr,
        const int* __restrict__ col,
        const float* __restrict__ inv_deg,
        float* __restrict__ out, int n) {
    int wave = threadIdx.x >> 6;
    int lane = threadIdx.x & 63;
    int node = blockIdx.x * 2 + wave;
    if (node >= n) return;
    int beg = row_ptr[node];
    int end = row_ptr[node + 1];
    const int quarter = lane >> 4;
    const int off = (lane & 15) << 2;     // half4 slice: 16 lanes x 4 halves = 64
    float a0f = 0.f, a1f = 0.f, a2f = 0.f, a3f = 0.f;
    for (int base = beg; base < end; base += 64) {
        int m = end - base;
        if (m > 64) m = 64;
        int myc = (lane < m) ? col[base + lane] : 0;
        int t = 0;
        for (; t + 4 <= (m >> 2); t += 4) {
            int u0 = __shfl(myc, ((t + 0) << 2) + quarter);
            int u1 = __shfl(myc, ((t + 1) << 2) + quarter);
            int u2 = __shfl(myc, ((t + 2) << 2) + quarter);
            int u3 = __shfl(myc, ((t + 3) << 2) + quarter);
            half4v v0 = *(const half4v*)&T[(size_t)u0 * 64 + off];
            half4v v1 = *(const half4v*)&T[(size_t)u1 * 64 + off];
            half4v v2 = *(const half4v*)&T[(size_t)u2 * 64 + off];
            half4v v3 = *(const half4v*)&T[(size_t)u3 * 64 + off];
            a0f += (float)v0[0] + (float)v1[0] + (float)v2[0] + (float)v3[0];
            a1f += (float)v0[1] + (float)v1[1] + (float)v2[1] + (float)v3[1];
            a2f += (float)v0[2] + (float)v1[2] + (float)v2[2] + (float)v3[2];
            a3f += (float)v0[3] + (float)v1[3] + (float)v2[3] + (float)v3[3];
        }
        int smax = (m + 3) >> 2;
        for (; t < smax; ++t) {
            int j = (t << 2) + quarter;
            int u = __shfl(myc, j);
            if (j < m) {
                half4v v = *(const half4v*)&T[(size_t)u * 64 + off];
                a0f += (float)v[0]; a1f += (float)v[1];
                a2f += (float)v[2]; a3f += (float)v[3];
            }
        }
    }
    a0f += __shfl(a0f, lane + 16); a1f += __shfl(a1f, lane + 16);
    a2f += __shfl(a2f, lane + 16); a3f += __shfl(a3f, lane + 16);
    a0f += __shfl(a0f, lane + 32); a1f += __shfl(a1f, lane + 32);
    a2f += __shfl(a2f, lane + 32); a3f += __shfl(a3f, lane + 32);
    if (quarter == 0) {
        float s = inv_deg[node];
        half4v r = *(const half4v*)&Rh[(size_t)node * 64 + off];
        float4 o;
        o.x = (float)r[0] + a0f * s;
        o.y = (float)r[1] + a1f * s;
        o.z = (float)r[2] + a2f * s;
        o.w = (float)r[3] + a3f * s;
        *(float4*)&out[(size_t)node * 64 + off] = o;
    }
}

// ---------------- MFMA GEMM, layers 0/1 (R3-proven) ----------------
template<int NT, bool RELU_HALF_OUT>
__global__ __launch_bounds__(128) void gemm_mfma_kernel(
        const _Float16* __restrict__ Xa, const _Float16* __restrict__ Xh,
        const _Float16* __restrict__ Wa, const _Float16* __restrict__ Wh,
        const float* __restrict__ bias,
        _Float16* __restrict__ out_h, float* __restrict__ out_f, int N) {
    const int wave = threadIdx.x >> 6;
    const int lane = threadIdx.x & 63;
    const int r16 = lane & 15;
    const int quad = lane >> 4;
    const int base = blockIdx.x * 64 + wave * 32;
    const int koff = quad * 8;

    floatx4 acc[2][NT];
    #pragma unroll
    for (int s = 0; s < 2; ++s)
        #pragma unroll
        for (int j = 0; j < NT; ++j)
            acc[s][j] = (floatx4){0.f, 0.f, 0.f, 0.f};

    #pragma unroll
    for (int hsel = 0; hsel < 2; ++hsel) {
        const _Float16* __restrict__ X = hsel ? Xh : Xa;
        const _Float16* __restrict__ W = hsel ? Wh : Wa;
        #pragma unroll
        for (int k0 = 0; k0 < 128; k0 += 32) {
            half8 a0 = *(const half8*)&X[(size_t)(base + r16) * 128 + k0 + koff];
            half8 a1 = *(const half8*)&X[(size_t)(base + 16 + r16) * 128 + k0 + koff];
            #pragma unroll
            for (int j = 0; j < NT; ++j) {
                half8 b = *(const half8*)&W[(size_t)(j * 16 + r16) * 128 + k0 + koff];
                acc[0][j] = __builtin_amdgcn_mfma_f32_16x16x32_f16(a0, b, acc[0][j], 0, 0, 0);
                acc[1][j] = __builtin_amdgcn_mfma_f32_16x16x32_f16(a1, b, acc[1][j], 0, 0, 0);
            }
        }
    }

    #pragma unroll
    for (int s = 0; s < 2; ++s) {
        #pragma unroll
        for (int i = 0; i < 4; ++i) {
            int r = base + s * 16 + quad * 4 + i;
            if (r >= N) continue;
            #pragma unroll
            for (int j = 0; j < NT; ++j) {
                int c = j * 16 + r16;
                float v = acc[s][j][i] + bias[c];
                if (RELU_HALF_OUT) {
                    v = fmaxf(v, 0.f);
                    out_h[(size_t)r * (NT * 16) + c] = (_Float16)v;
                } else {
                    out_f[(size_t)r * (NT * 16) + c] = v;
                }
            }
        }
    }
}

// ---- dual GEMM, layer 2: T = B@Wl^T (fp16), Rh = B@Wr^T + bias (fp16) ----
__global__ __launch_bounds__(128) void gemm_dual_kernel(
        const _Float16* __restrict__ B, const _Float16* __restrict__ Wl,
        const _Float16* __restrict__ Wr, const float* __restrict__ bias,
        _Float16* __restrict__ T, _Float16* __restrict__ Rh, int N) {
    const int wave = threadIdx.x >> 6;
    const int lane = threadIdx.x & 63;
    const int r16 = lane & 15;
    const int quad = lane >> 4;
    const int base = blockIdx.x * 64 + wave * 32;
    const int koff = quad * 8;

    floatx4 accT[2][4], accR[2][4];
    #pragma unroll
    for (int s = 0; s < 2; ++s)
        #pragma unroll
        for (int j = 0; j < 4; ++j) {
            accT[s][j] = (floatx4){0.f, 0.f, 0.f, 0.f};
            accR[s][j] = (floatx4){0.f, 0.f, 0.f, 0.f};
        }

    #pragma unroll
    for (int k0 = 0; k0 < 128; k0 += 32) {
        half8 a0 = *(const half8*)&B[(size_t)(base + r16) * 128 + k0 + koff];
        half8 a1 = *(const half8*)&B[(size_t)(base + 16 + r16) * 128 + k0 + koff];
        #pragma unroll
        for (int j = 0; j < 4; ++j) {
            half8 bl = *(const half8*)&Wl[(size_t)(j * 16 + r16) * 128 + k0 + koff];
            half8 br = *(const half8*)&Wr[(size_t)(j * 16 + r16) * 128 + k0 + koff];
            accT[0][j] = __builtin_amdgcn_mfma_f32_16x16x32_f16(a0, bl, accT[0][j], 0, 0, 0);
            accT[1][j] = __builtin_amdgcn_mfma_f32_16x16x32_f16(a1, bl, accT[1][j], 0, 0, 0);
            accR[0][j] = __builtin_amdgcn_mfma_f32_16x16x32_f16(a0, br, accR[0][j], 0, 0, 0);
            accR[1][j] = __builtin_amdgcn_mfma_f32_16x16x32_f16(a1, br, accR[1][j], 0, 0, 0);
        }
    }

    #pragma unroll
    for (int s = 0; s < 2; ++s) {
        #pragma unroll
        for (int i = 0; i < 4; ++i) {
            int r = base + s * 16 + quad * 4 + i;
            if (r >= N) continue;
            #pragma unroll
            for (int j = 0; j < 4; ++j) {
                int c = j * 16 + r16;
                T[(size_t)r * 64 + c]  = (_Float16)accT[s][j][i];
                Rh[(size_t)r * 64 + c] = (_Float16)(accR[s][j][i] + bias[c]);
            }
        }
    }
}

extern "C" void kernel_launch(void* const* d_in, const int* in_sizes, int n_in,
                              void* d_out, int out_size, void* d_ws, size_t ws_size,
                              hipStream_t stream) {
    const float* x   = (const float*)d_in[0];
    const int*   edge = (const int*)d_in[1];   // int32: [2, E]
    const float* Wl0 = (const float*)d_in[2];
    const float* bl0 = (const float*)d_in[3];
    const float* Wr0 = (const float*)d_in[4];
    const float* Wl1 = (const float*)d_in[5];
    const float* bl1 = (const float*)d_in[6];
    const float* Wr1 = (const float*)d_in[7];
    const float* Wl2 = (const float*)d_in[8];
    const float* bl2 = (const float*)d_in[9];
    const float* Wr2 = (const float*)d_in[10];
    float* out = (float*)d_out;

    const int N = in_sizes[0] / D_H;   // 50000
    const int E = in_sizes[1] / 2;     // 800000
    const int* src = edge;
    const int* dst = edge + E;

    const int gx = (N + 63) / 64;
    const int Np = gx * 64;
    const size_t HBYTES = (size_t)Np * D_H * 2;   // 12.8MB per fp16 node matrix

    // ---- time-multiplexed workspace (~42MB) ----
    char* w = (char*)d_ws;
    char* P0 = w;  w += HBYTES;
    char* P1 = w;  w += HBYTES;
    char* P2 = w;  w += HBYTES;
    _Float16* Wl0h = (_Float16*)w;  w += (size_t)128 * 128 * 2;
    _Float16* Wr0h = (_Float16*)w;  w += (size_t)128 * 128 * 2;
    _Float16* Wl1h = (_Float16*)w;  w += (size_t)128 * 128 * 2;
    _Float16* Wr1h = (_Float16*)w;  w += (size_t)128 * 128 * 2;
    _Float16* Wl2h = (_Float16*)w;  w += (size_t)64 * 128 * 2;
    _Float16* Wr2h = (_Float16*)w;  w += (size_t)64 * 128 * 2;
    int* row_ptr = (int*)w;      w += (size_t)(N + 16) * 4;
    float* inv_deg = (float*)w;  w += (size_t)N * 4;
    int* col     = (int*)w;      w += (size_t)E * 4;
    int* histo   = (int*)w;      w += (size_t)NBLK * NBUCKET * 4;
    int* offs    = (int*)w;      w += (size_t)NBLK * NBUCKET * 4;
    int* boff    = (int*)w;      w += (size_t)(NBUCKET + 1) * 4;

    _Float16* xh   = (_Float16*)P0;
    _Float16* Bh   = (_Float16*)P0;          // xh dead after layer-0 GEMM
    unsigned int* bedge = (unsigned int*)P1; // 3.2MB, dead after bucket_build
    _Float16* Ah   = (_Float16*)P1;
    _Float16* aggh = (_Float16*)P2;          // dead after layer-1 GEMM
    _Float16* T    = (_Float16*)P2;                       // layer-2 T (6.4MB)
    _Float16* Rh   = (_Float16*)(P2 + HBYTES / 2);        // layer-2 Rh (6.4MB)

    // ---- CSR step 1 + conversions (one dispatch) ----
    const int n4 = N * D_H / 4;
    const int conv_blocks = (n4 + 20480 + 255) / 256;
    hist_convert_kernel<<<NBLK + conv_blocks, 256, 0, stream>>>(
        dst, histo, E, x, xh, n4,
        Wl0, Wr0, Wl1, Wr1, Wl2, Wr2,
        Wl0h, Wr0h, Wl1h, Wr1h, Wl2h, Wr2h);

    // ---- CSR steps 2-4 ----
    scan_hist_kernel<<<1, 256, 0, stream>>>(histo, offs, boff, row_ptr, N);
    scatter_kernel<<<NBLK, 256, 0, stream>>>(src, dst, offs, bedge, E);
    bucket_build_kernel<<<NBUCKET, 256, 0, stream>>>(bedge, boff, row_ptr, inv_deg, col, N);

    const int agg_grid = (N + 1) / 2;     // 2 nodes per 128-thread block

    // ---- layer 0: xh -> Ah (relu) ----
    aggregate_kernel<<<agg_grid, 128, 0, stream>>>(xh, row_ptr, col, inv_deg, aggh, N);
    gemm_mfma_kernel<8, true><<<gx, 128, 0, stream>>>(aggh, xh, Wl0h, Wr0h, bl0, Ah, nullptr, N);

    // ---- layer 1: Ah -> Bh (relu; Bh overwrites xh region) ----
    aggregate_kernel<<<agg_grid, 128, 0, stream>>>(Ah, row_ptr, col, inv_deg, aggh, N);
    gemm_mfma_kernel<8, true><<<gx, 128, 0, stream>>>(aggh, Ah, Wl1h, Wr1h, bl1, Bh, nullptr, N);

    // ---- layer 2 (reordered): T = Bh@Wl2^T, Rh = Bh@Wr2^T + bias (fp16),
    //      then out = Rh + inv_deg * (A @ T) with 64-dim (128B) gathers ----
    gemm_dual_kernel<<<gx, 128, 0, stream>>>(Bh, Wl2h, Wr2h, bl2, T, Rh, N);
    aggregate_add64_kernel<<<agg_grid, 128, 0, stream>>>(T, Rh, row_ptr, col,
                                                         inv_deg, out, N);
}